// Round 2
// baseline (426.020 us; speedup 1.0000x reference)
//
#include <hip/hip_runtime.h>
#include <hip/hip_bf16.h>

typedef __bf16 bf16_t;
typedef __attribute__((ext_vector_type(8))) __bf16 bf16x8;
typedef __attribute__((ext_vector_type(4))) __bf16 bf16x4;
typedef __attribute__((ext_vector_type(4))) float floatx4;

// Problem shape (fixed by reference): B=8, canvas 64x64 -> N=4096, D=CV=128.
// Reference dtype is FLOAT32 (in and out). We convert to bf16 for MFMA,
// accumulate fp32; threshold is 2% of max|ref| -> bf16 compute fits easily.
static constexpr int NSEQ = 4096;
static constexpr int DIM  = 128;
static constexpr int BATCH = 8;
static constexpr size_t NELEM = (size_t)BATCH * NSEQ * DIM;       // 4194304
static constexpr size_t WS_NEED = 3 * NELEM * sizeof(bf16_t);      // 24 MiB

// 1/sqrt(128) * log2(e): fold softmax scale into exp2 (v_exp_f32 is 2^x)
static constexpr float SCALE_LOG2E = 0.08838834764831845f * 1.4426950408889634f;

// ---------- conversion kernels (fast path, uses d_ws) ----------

__global__ __launch_bounds__(256)
void cvt_qk_kernel(const float* __restrict__ Q, const float* __restrict__ K,
                   bf16_t* __restrict__ Qb, bf16_t* __restrict__ Kb) {
  const size_t n4 = NELEM / 4;
  for (size_t i = (size_t)blockIdx.x * blockDim.x + threadIdx.x; i < n4;
       i += (size_t)gridDim.x * blockDim.x) {
    float4 q = ((const float4*)Q)[i];
    float4 k = ((const float4*)K)[i];
    bf16x4 qv = {(__bf16)q.x, (__bf16)q.y, (__bf16)q.z, (__bf16)q.w};
    bf16x4 kv = {(__bf16)k.x, (__bf16)k.y, (__bf16)k.z, (__bf16)k.w};
    ((bf16x4*)Qb)[i] = qv;
    ((bf16x4*)Kb)[i] = kv;
  }
}

// V [B][4096][128] fp32  ->  Vt [B][128][4096] bf16 (LDS 32x32 tile transpose)
__global__ __launch_bounds__(256)
void cvt_vt_kernel(const float* __restrict__ V, bf16_t* __restrict__ Vt) {
  __shared__ bf16_t tile[32][33];          // +1 pad breaks bank alignment
  const int bid = blockIdx.x;              // 8 * 128 * 4 = 4096 blocks
  const int b   = bid >> 9;
  const int rem = bid & 511;
  const int kt  = rem >> 2;                // 32-key tile, 0..127
  const int nt  = rem & 3;                 // 32-dim tile, 0..3
  const int tx  = threadIdx.x & 31;
  const int ty  = threadIdx.x >> 5;        // 0..7
  const float* Vb = V + ((size_t)b * NSEQ + kt * 32) * DIM + nt * 32;
  #pragma unroll
  for (int i = 0; i < 4; ++i) {
    int k = ty + i * 8;                    // key within tile
    tile[k][tx] = (__bf16)Vb[(size_t)k * DIM + tx];   // coalesced fp32 read
  }
  __syncthreads();
  bf16_t* Vtb = Vt + ((size_t)b * DIM + nt * 32) * NSEQ + kt * 32;
  #pragma unroll
  for (int i = 0; i < 4; ++i) {
    int n = ty + i * 8;                    // dim within tile
    Vtb[(size_t)n * NSEQ + tx] = tile[tx][n];          // coalesced bf16 write
  }
}

// ---------- flash attention ----------

__device__ inline bf16x8 ld8_f32(const float* p) {
  float4 a = *(const float4*)p;
  float4 b = *(const float4*)(p + 4);
  bf16x8 r = {(__bf16)a.x, (__bf16)a.y, (__bf16)a.z, (__bf16)a.w,
              (__bf16)b.x, (__bf16)b.y, (__bf16)b.z, (__bf16)b.w};
  return r;
}

// FAST: Qp/Kp are bf16 rows, Vp is bf16 TRANSPOSED [dim][key].
// !FAST: all raw fp32 in reference layout (scalar V gather).
template <bool FAST>
__global__ __launch_bounds__(256)
void causal_attn_kernel(const void* __restrict__ Qp, const void* __restrict__ Kp,
                        const void* __restrict__ Vp, float* __restrict__ Out) {
  // Per-wave P-transpose scratch: 16 rows x 32 keys, stride 40 bf16 (80 B,
  // 16B-aligned rows). 4 waves.
  __shared__ bf16_t p_lds[4][16 * 40];

  const int bid  = blockIdx.x;
  const int t    = bid >> 3;      // 0..63 qtile-pair index
  const int b    = bid & 7;       // batch
  const int tid  = (int)threadIdx.x;
  const int wave = tid >> 6;
  const int lane = tid & 63;
  const int l16  = lane & 15;
  const int quad = lane >> 4;

  // Waves 0,1 -> qtile t; waves 2,3 -> qtile 127-t: constant work per block.
  const int qtile  = (wave < 2) ? t : (127 - t);
  const int q_base = qtile * 32 + (wave & 1) * 16;
  const int q_end  = q_base + 16;

  // Q fragments: A-layout A[m=l16][k=quad*8+j], 4 frags cover D=128
  bf16x8 qf[4];
  {
    const size_t off = ((size_t)b * NSEQ + q_base + l16) * DIM + quad * 8;
    if constexpr (FAST) {
      const bf16_t* qrow = (const bf16_t*)Qp + off;
      #pragma unroll
      for (int d = 0; d < 4; ++d)
        qf[d] = *reinterpret_cast<const bf16x8*>(qrow + 32 * d);
    } else {
      const float* qrow = (const float*)Qp + off;
      #pragma unroll
      for (int d = 0; d < 4; ++d) qf[d] = ld8_f32(qrow + 32 * d);
    }
  }

  floatx4 acc[8];
  #pragma unroll
  for (int c = 0; c < 8; ++c) acc[c] = (floatx4){0.f, 0.f, 0.f, 0.f};
  float m_run[4] = {-3.0e38f, -3.0e38f, -3.0e38f, -3.0e38f};
  float l_run[4] = {0.f, 0.f, 0.f, 0.f};

  bf16_t* pl = p_lds[wave];
  const int ntiles = (q_end + 31) >> 5;

  for (int kt = 0; kt < ntiles; ++kt) {
    const int kb = kt * 32;

    // ---- S = Q K^T for 32 keys (two 16-col chunks), fp32 accumulate ----
    floatx4 s0 = {0.f, 0.f, 0.f, 0.f};
    floatx4 s1 = {0.f, 0.f, 0.f, 0.f};
    {
      const size_t koff = ((size_t)b * NSEQ + kb + l16) * DIM + quad * 8;
      if constexpr (FAST) {
        const bf16_t* k0 = (const bf16_t*)Kp + koff;
        const bf16_t* k1 = k0 + 16 * DIM;
        #pragma unroll
        for (int d = 0; d < 4; ++d) {
          bf16x8 kf = *reinterpret_cast<const bf16x8*>(k0 + 32 * d);
          s0 = __builtin_amdgcn_mfma_f32_16x16x32_bf16(qf[d], kf, s0, 0, 0, 0);
        }
        #pragma unroll
        for (int d = 0; d < 4; ++d) {
          bf16x8 kf = *reinterpret_cast<const bf16x8*>(k1 + 32 * d);
          s1 = __builtin_amdgcn_mfma_f32_16x16x32_bf16(qf[d], kf, s1, 0, 0, 0);
        }
      } else {
        const float* k0 = (const float*)Kp + koff;
        const float* k1 = k0 + 16 * DIM;
        #pragma unroll
        for (int d = 0; d < 4; ++d) {
          bf16x8 kf = ld8_f32(k0 + 32 * d);
          s0 = __builtin_amdgcn_mfma_f32_16x16x32_bf16(qf[d], kf, s0, 0, 0, 0);
        }
        #pragma unroll
        for (int d = 0; d < 4; ++d) {
          bf16x8 kf = ld8_f32(k1 + 32 * d);
          s1 = __builtin_amdgcn_mfma_f32_16x16x32_bf16(qf[d], kf, s1, 0, 0, 0);
        }
      }
    }

    // ---- online softmax; rows live in 16-lane quad-groups ----
    float alpha[4];
    #pragma unroll
    for (int r = 0; r < 4; ++r) {
      const int qi = q_base + quad * 4 + r;
      float v0 = s0[r] * SCALE_LOG2E;
      float v1 = s1[r] * SCALE_LOG2E;
      v0 = (kb + l16      <= qi) ? v0 : -3.0e38f;
      v1 = (kb + 16 + l16 <= qi) ? v1 : -3.0e38f;
      float mx = fmaxf(v0, v1);
      #pragma unroll
      for (int off = 1; off < 16; off <<= 1)
        mx = fmaxf(mx, __shfl_xor(mx, off, 64));
      const float m_new = fmaxf(m_run[r], mx);
      alpha[r] = __builtin_amdgcn_exp2f(m_run[r] - m_new);
      m_run[r] = m_new;
      const float p0 = __builtin_amdgcn_exp2f(v0 - m_new);  // masked -> 0
      const float p1 = __builtin_amdgcn_exp2f(v1 - m_new);
      float rs = p0 + p1;
      #pragma unroll
      for (int off = 1; off < 16; off <<= 1)
        rs += __shfl_xor(rs, off, 64);
      l_run[r] = l_run[r] * alpha[r] + rs;
      pl[(quad * 4 + r) * 40 + l16]      = (__bf16)p0;   // stage P for
      pl[(quad * 4 + r) * 40 + 16 + l16] = (__bf16)p1;   // C->A transpose
    }

    // wave-internal LDS round trip (per-wave scratch, no __syncthreads)
    asm volatile("s_waitcnt lgkmcnt(0)" ::: "memory");
    const bf16x8 pf =
        *reinterpret_cast<const bf16x8*>(pl + l16 * 40 + quad * 8);

    #pragma unroll
    for (int c = 0; c < 8; ++c) {
      #pragma unroll
      for (int r = 0; r < 4; ++r) acc[c][r] *= alpha[r];
    }

    // ---- O += P(16x32) * V(32x128) ----
    if constexpr (FAST) {
      const bf16_t* vt = (const bf16_t*)Vp + (size_t)b * DIM * NSEQ + kb + quad * 8;
      #pragma unroll
      for (int c = 0; c < 8; ++c) {
        bf16x8 vf = *reinterpret_cast<const bf16x8*>(vt + (size_t)(c * 16 + l16) * NSEQ);
        acc[c] = __builtin_amdgcn_mfma_f32_16x16x32_bf16(pf, vf, acc[c], 0, 0, 0);
      }
    } else {
      const float* vb = (const float*)Vp + ((size_t)b * NSEQ + kb + quad * 8) * DIM + l16;
      #pragma unroll
      for (int c = 0; c < 8; ++c) {
        bf16x8 vf;
        const float* vcol = vb + c * 16;
        #pragma unroll
        for (int j = 0; j < 8; ++j) vf[j] = (__bf16)vcol[(size_t)j * DIM];
        acc[c] = __builtin_amdgcn_mfma_f32_16x16x32_bf16(pf, vf, acc[c], 0, 0, 0);
      }
    }
  }

  // ---- epilogue: normalize, store fp32 ----
  float inv_l[4];
  #pragma unroll
  for (int r = 0; r < 4; ++r) inv_l[r] = 1.0f / l_run[r];

  float* orow = Out + ((size_t)b * NSEQ + q_base + quad * 4) * DIM + l16;
  #pragma unroll
  for (int c = 0; c < 8; ++c) {
    #pragma unroll
    for (int r = 0; r < 4; ++r)
      orow[(size_t)r * DIM + c * 16] = acc[c][r] * inv_l[r];
  }
}

extern "C" void kernel_launch(void* const* d_in, const int* in_sizes, int n_in,
                              void* d_out, int out_size, void* d_ws, size_t ws_size,
                              hipStream_t stream) {
  const float* Q = (const float*)d_in[0];
  const float* K = (const float*)d_in[1];
  const float* V = (const float*)d_in[2];
  float* Out = (float*)d_out;
  (void)in_sizes; (void)n_in; (void)out_size;

  dim3 block(256);
  if (ws_size >= WS_NEED) {
    bf16_t* Qb = (bf16_t*)d_ws;
    bf16_t* Kb = Qb + NELEM;
    bf16_t* Vt = Kb + NELEM;
    cvt_qk_kernel<<<dim3(2048), block, 0, stream>>>(Q, K, Qb, Kb);
    cvt_vt_kernel<<<dim3(4096), block, 0, stream>>>(V, Vt);
    causal_attn_kernel<true><<<dim3(512), block, 0, stream>>>(Qb, Kb, Vt, Out);
  } else {
    causal_attn_kernel<false><<<dim3(512), block, 0, stream>>>(Q, K, V, Out);
  }
}